// Round 11
// baseline (383.184 us; speedup 1.0000x reference)
//
#include <hip/hip_runtime.h>

// Gram-trick + MFMA. Ladder: 2310 -> ... -> 462 -> 392 -> (425) -> 363 -> (384) -> 351 -> 352.
// R23: gram v6 — ks split 16->32 (grid 672->1344, 2.6->5 blocks/CU). R16's
// attempt at this regressed because of the ATOMIC epilogue (RMW doubled);
// R17 removed atomics, so the TLP lever is now safe: only the streaming
// Gpart write doubles (44->88MB). greduce sums 32 L3-resident slices.
// ws_size-guarded (needs 171MB; observed 256MiB) with ks=16 fallback.

#define HW 16384
typedef unsigned short u16;
typedef unsigned int u32;
typedef __attribute__((ext_vector_type(8))) short short8;
typedef __attribute__((ext_vector_type(4))) float f32x4;

// staging offsets (u16 elements)
#define S_CEN 0
#define S_QW 1048576
#define S_KW 1056768
#define S_VW 1581056
#define S_W1 2105344
#define S_B1 2142208
#define S_W2 2142336
#define S_B2 2143360
#define S_SW 2143392
#define S_OW 2143400
#define S_GAMMA 2208936
#define S_BETA 2209192
#define S_TOTAL 2209456

// compact Gram layout per batch (f32 elements)
#define G_D1 0       // 128x128, stride 128
#define G_D2 16384   // 128x1024, stride 1024
#define G_S 147456   // 4 blocks of 256x256, stride 256
#define G_SZ 409600

// partial-G: 21 tiles x 16384 per (b,ks) slot
#define GP_SLOT 344064

__device__ __forceinline__ float b2f(u16 u) { return __uint_as_float(((u32)u) << 16); }
__device__ __forceinline__ u16 f2b(float f) {
  u32 u = __float_as_uint(f);
  return (u16)((u + 0x7FFFu + ((u >> 16) & 1u)) >> 16);  // RNE
}
__device__ __forceinline__ float wave_sum(float v) {
  #pragma unroll
  for (int off = 32; off > 0; off >>= 1) v += __shfl_xor(v, off, 64);
  return v;
}
__device__ __forceinline__ float wave_max(float v) {
  #pragma unroll
  for (int off = 32; off > 0; off >>= 1) v = fmaxf(v, __shfl_xor(v, off, 64));
  return v;
}
__device__ __forceinline__ void unpack8(uint4 v, float* f) {
  f[0] = __uint_as_float(v.x << 16); f[1] = __uint_as_float(v.x & 0xFFFF0000u);
  f[2] = __uint_as_float(v.y << 16); f[3] = __uint_as_float(v.y & 0xFFFF0000u);
  f[4] = __uint_as_float(v.z << 16); f[5] = __uint_as_float(v.z & 0xFFFF0000u);
  f[6] = __uint_as_float(v.w << 16); f[7] = __uint_as_float(v.w & 0xFFFF0000u);
}
__device__ __forceinline__ void gload16(const u16* g, u16* l) {
  __builtin_amdgcn_global_load_lds(
      (const __attribute__((address_space(1))) void*)g,
      (__attribute__((address_space(3))) void*)l, 16, 0, 0);
}

// tile -> (r0, c0, goff, gstride) decode, shared by gram_mfma / greduce
__device__ __forceinline__ void tile_decode(int tile, int& r0, int& c0,
                                            size_t& goff, int& gstride) {
  if (tile == 0) { r0 = 0; c0 = 0; goff = G_D1; gstride = 128; }
  else if (tile < 9) { r0 = 0; c0 = 128 * tile; goff = G_D2 + (size_t)(tile - 1) * 128; gstride = 1024; }
  else if (tile < 17) {
    int t2 = tile - 9; int j = t2 >> 1, p = t2 & 1;
    r0 = 128 + 256 * j + 128 * p; c0 = r0;
    goff = G_S + (size_t)j * 65536 + (size_t)p * (128 * 256 + 128); gstride = 256;
  } else {
    int j = tile - 17;
    r0 = 128 + 256 * j; c0 = r0 + 128;
    goff = G_S + (size_t)j * 65536 + 128; gstride = 256;
  }
}

// ------------------------------------------------------------ dtype probe
__global__ void probe(const u32* __restrict__ g, int* __restrict__ flag) {
  if (threadIdx.x == 0) {
    int ok = 1;
    #pragma unroll
    for (int i = 0; i < 4; i++) {
      u32 w = g[i];
      u32 lo = w & 0xFFFFu, hi = w >> 16;
      ok &= (lo >= 0x3E00u && lo <= 0x4100u) ? 1 : 0;
      ok &= (hi >= 0x3E00u && hi <= 0x4100u) ? 1 : 0;
    }
    *flag = ok ? 0 : 1;  // 0 = bf16 inputs, 1 = f32 inputs
  }
}

// ------------------------------------------------------------ stage inputs -> bf16
__global__ __launch_bounds__(256) void convert_all(
    const void* p0, const void* p1, const void* p2, const void* p3,
    const void* p4, const void* p5, const void* p6, const void* p7,
    const void* p8, const void* p9, const void* p10, const void* p11,
    u16* __restrict__ S, const int* __restrict__ flag) {
  const void* src; int n; int off;
  switch (blockIdx.z) {
    case 0:  src = p0;  n = 1048576; off = S_CEN; break;
    case 1:  src = p1;  n = 8192;    off = S_QW; break;
    case 2:  src = p2;  n = 524288;  off = S_KW; break;
    case 3:  src = p3;  n = 524288;  off = S_VW; break;
    case 4:  src = p4;  n = 36864;   off = S_W1; break;
    case 5:  src = p5;  n = 128;     off = S_B1; break;
    case 6:  src = p6;  n = 1024;    off = S_W2; break;
    case 7:  src = p7;  n = 32;      off = S_B2; break;
    case 8:  src = p8;  n = 8;       off = S_SW; break;
    case 9:  src = p9;  n = 65536;   off = S_OW; break;
    case 10: src = p10; n = 256;     off = S_GAMMA; break;
    default: src = p11; n = 256;     off = S_BETA; break;
  }
  int idx = (blockIdx.x * 256 + threadIdx.x) * 4;
  if (idx >= n) return;
  u16* dst = S + off + idx;
  if (*flag) {
    float4 v = ((const float4*)src)[idx >> 2];
    dst[0] = f2b(v.x); dst[1] = f2b(v.y); dst[2] = f2b(v.z); dst[3] = f2b(v.w);
  } else {
    *(ushort4*)dst = ((const ushort4*)src)[idx >> 2];
  }
}

// ---- transp: cen[b][ci][s] -> cenT[b][s][ci]  (LDS-tiled, 2 MB total)
__global__ __launch_bounds__(256) void transp(
    const u16* __restrict__ cen, u16* __restrict__ cenT) {
  __shared__ u16 tile[32][258];
  const int t = threadIdx.x;
  const int s0 = blockIdx.x * 256;
  const u16* cb = cen + (size_t)blockIdx.y * 32 * HW;
  for (int e = t; e < 2048; e += 256) {
    int ci = e >> 6, sx = (e & 63) * 4;
    *(u32*)&tile[ci][sx] = *(const u32*)&cb[(size_t)ci * HW + s0 + sx];
    *(u32*)&tile[ci][sx + 2] = *(const u32*)&cb[(size_t)ci * HW + s0 + sx + 2];
  }
  __syncthreads();
  u16* ob = cenT + (size_t)blockIdx.y * HW * 32;
  for (int e = t; e < 1024; e += 256) {
    int px = e >> 2, cg = (e & 3) * 8;
    u16 tmp[8];
    #pragma unroll
    for (int k = 0; k < 8; k++) tmp[k] = tile[cg + k][px];
    *(uint4*)&ob[(size_t)(s0 + px) * 32 + cg] = *(uint4*)tmp;
  }
}

// --- sur_w v9: conv via MFMA im2col. Block = 1 image row (128 px), one z.
__global__ __launch_bounds__(256) void sur_w(
    const u16* __restrict__ cenT, const u16* __restrict__ w1g,
    const u16* __restrict__ b1g, const u16* __restrict__ w2g,
    const u16* __restrict__ zbuf, float* __restrict__ lgbuf) {
  const int z = blockIdx.y;            // b*4+si
  const int b = z >> 2, si = z & 3, d = 1 << si;
  const int hh = blockIdx.x;           // image row 0..127
  __shared__ __align__(16) char smem[27776];
  u16* Bs = (u16*)smem;                // 8 KB   [128 px][32 ci] (chunk-swizzled)
  u16* w1s = (u16*)(smem + 8192);      // 18 KB  [9][32 co][32 ci] (chunk-swizzled)
  float* h1s = (float*)smem;           // 16.9 KB [128][33], aliases Bs/w1s post-taps
  __shared__ float w2s[8][32];
  __shared__ float b1s[32];
  const int t = threadIdx.x;
  for (int e = t; e < 9216; e += 256) {
    int tap = e >> 10, rem = e & 1023, co = rem >> 5, ci = rem & 31;
    int dst = tap * 1024 + co * 32 + ((((ci >> 3) ^ (co & 3)) << 3) | (ci & 7));
    w1s[dst] = w1g[si * 9216 + co * 288 + ci * 9 + tap];
  }
  w2s[t >> 5][t & 31] = b2f(w2g[si * 256 + t]);
  if (t < 32) b1s[t] = b2f(b1g[si * 32 + t]);

  const u16* cb = cenT + (size_t)b * HW * 32;
  const int lane = t & 63, w = t >> 6;
  const int m = lane & 15, quad = lane >> 4;
  const int slot8 = (quad ^ (m & 3)) << 3;   // swizzled k-chunk for frag reads
  f32x4 acc[2][2];
  #pragma unroll
  for (int i = 0; i < 2; i++)
    #pragma unroll
    for (int j = 0; j < 2; j++) acc[i][j] = (f32x4){0.f, 0.f, 0.f, 0.f};

  for (int tap = 0; tap < 9; tap++) {
    const int ky = tap / 3, kx = tap - ky * 3;
    const int y = hh + (ky - 1) * d;
    if (y < 0 || y > 127) continue;          // uniform: zero contribution
    const int dx = (kx - 1) * d;
    #pragma unroll
    for (int q = 0; q < 2; q++) {
      const int e = q * 256 + t;
      const int px = e >> 2, ck = e & 3;
      const int x = px + dx;
      const u16* src = ((unsigned)x < 128u)
          ? cb + ((size_t)(y * 128 + x) * 32 + ((ck ^ (px & 3)) << 3))
          : zbuf;
      gload16(src, Bs + (size_t)e * 8);
    }
    __syncthreads();
    short8 af[2], bf[2];
    #pragma unroll
    for (int i = 0; i < 2; i++)
      af[i] = *(const short8*)&Bs[(w * 32 + i * 16 + m) * 32 + slot8];
    #pragma unroll
    for (int j = 0; j < 2; j++)
      bf[j] = *(const short8*)&w1s[tap * 1024 + (j * 16 + m) * 32 + slot8];
    #pragma unroll
    for (int i = 0; i < 2; i++)
      #pragma unroll
      for (int j = 0; j < 2; j++)
        acc[i][j] = __builtin_amdgcn_mfma_f32_16x16x32_bf16(af[i], bf[j], acc[i][j], 0, 0, 0);
    __syncthreads();
  }

  #pragma unroll
  for (int i = 0; i < 2; i++)
    #pragma unroll
    for (int j = 0; j < 2; j++) {
      const int co = j * 16 + m;
      #pragma unroll
      for (int r = 0; r < 4; r++) {
        const int px = w * 32 + i * 16 + quad * 4 + r;
        h1s[px * 33 + co] = fmaxf(acc[i][j][r] + b1s[co], 0.f);
      }
    }
  __syncthreads();

  const int px = t >> 1, half = t & 1;
  float lp[4];
  #pragma unroll
  for (int k = 0; k < 4; k++) lp[k] = 0.f;
  #pragma unroll
  for (int i = 0; i < 32; i++) {
    const float v = h1s[px * 33 + i];
    #pragma unroll
    for (int k = 0; k < 4; k++) lp[k] = fmaf(v, w2s[half * 4 + k][i], lp[k]);
  }
  float* dst = lgbuf + ((size_t)z * HW + hh * 128 + px) * 8 + half * 4;
  *(float4*)dst = make_float4(lp[0], lp[1], lp[2], lp[3]);
}

// --- sur_scatter v4: read full logits [z][s][8], softmax, neighbors + sur writes
__global__ __launch_bounds__(256) void sur_scatter(
    const u16* __restrict__ cen, const float* __restrict__ lgbuf,
    const u16* __restrict__ b2g, const u16* __restrict__ swg,
    u16* __restrict__ Mbuf) {
  const int z = blockIdx.z;
  const int b = z >> 2, si = z & 3, d = 1 << si;
  const int c0 = blockIdx.y * 8;
  const int t = threadIdx.x;
  const int s = (blockIdx.x * 256 + t) * 2;  // even
  const int h = s >> 7, w = s & 127;

  float s0 = b2f(swg[si * 2 + 0]), s1 = b2f(swg[si * 2 + 1]);
  float mx = fmaxf(s0, s1);
  float e0 = expf(s0 - mx), e1 = expf(s1 - mx);
  float w20 = e0 / (e0 + e1), w21 = e1 / (e0 + e1);

  float b2s[8];
  #pragma unroll
  for (int k = 0; k < 8; k++) b2s[k] = b2f(b2g[si * 8 + k]);

  const float* lpa = lgbuf + ((size_t)z * HW + s) * 8;
  float lga[8], lgb[8];
  {
    float4 a0 = *(const float4*)lpa,       a1 = *(const float4*)(lpa + 4);
    float4 g0 = *(const float4*)(lpa + 8), g1 = *(const float4*)(lpa + 12);
    lga[0] = a0.x; lga[1] = a0.y; lga[2] = a0.z; lga[3] = a0.w;
    lga[4] = a1.x; lga[5] = a1.y; lga[6] = a1.z; lga[7] = a1.w;
    lgb[0] = g0.x; lgb[1] = g0.y; lgb[2] = g0.z; lgb[3] = g0.w;
    lgb[4] = g1.x; lgb[5] = g1.y; lgb[6] = g1.z; lgb[7] = g1.w;
  }
  {
    #pragma unroll
    for (int k = 0; k < 8; k++) lga[k] += b2s[k];
    float lm = lga[0];
    #pragma unroll
    for (int k = 1; k < 8; k++) lm = fmaxf(lm, lga[k]);
    float ls = 0.f;
    #pragma unroll
    for (int k = 0; k < 8; k++) { lga[k] = expf(lga[k] - lm); ls += lga[k]; }
    float inv = w20 / ls;
    #pragma unroll
    for (int k = 0; k < 8; k++) lga[k] *= inv;
  }
  {
    #pragma unroll
    for (int k = 0; k < 8; k++) lgb[k] += b2s[k];
    float lm = lgb[0];
    #pragma unroll
    for (int k = 1; k < 8; k++) lm = fmaxf(lm, lgb[k]);
    float ls = 0.f;
    #pragma unroll
    for (int k = 0; k < 8; k++) { lgb[k] = expf(lgb[k] - lm); ls += lgb[k]; }
    float inv = w20 / ls;
    #pragma unroll
    for (int k = 0; k < 8; k++) lgb[k] *= inv;
  }

  const int dy[8] = {-d, -d, -d, 0, 0, d, d, d};
  const int dx[8] = {-d, 0, d, -d, d, -d, 0, d};
  int offa[8], offb[8];
  #pragma unroll
  for (int k = 0; k < 8; k++) {
    int y = h + dy[k]; y = y < 0 ? -y : (y > 127 ? 254 - y : y);
    int xa = w + dx[k]; xa = xa < 0 ? -xa : (xa > 127 ? 254 - xa : xa);
    int xb = w + 1 + dx[k]; xb = xb < 0 ? -xb : (xb > 127 ? 254 - xb : xb);
    offa[k] = y * 128 + xa;
    offb[k] = y * 128 + xb;
  }
  const u16* cb = cen + (size_t)b * 32 * HW;
  u16* Mb = Mbuf + (size_t)b * 1152 * HW;
  for (int c = c0; c < c0 + 8; c++) {
    const u16* cc = cb + (size_t)c * HW;
    u32 cvp = *(const u32*)&cc[s];
    float cva = __uint_as_float(cvp << 16), cvb = __uint_as_float(cvp & 0xFFFF0000u);
    float nba[8], nbb[8];
    #pragma unroll
    for (int k = 0; k < 8; k++) { nba[k] = b2f(cc[offa[k]]); nbb[k] = b2f(cc[offb[k]]); }
    float sxa = 0.f, mna = 0.f, sxb = 0.f, mnb = 0.f;
    #pragma unroll
    for (int k = 0; k < 8; k++) {
      sxa = fmaf(lga[k], nba[k], sxa); mna += nba[k];
      sxb = fmaf(lgb[k], nbb[k], sxb); mnb += nbb[k];
    }
    float suma = sxa + cva * w21, sumb = sxb + cvb * w21;
    u32 cx = (u32)f2b(mna * 0.125f * w20 + cva * w21) |
             ((u32)f2b(mnb * 0.125f * w20 + cvb * w21) << 16);
    *(u32*)&Mb[(size_t)(32 * si + c) * HW + s] = cx;
    #pragma unroll
    for (int k = 0; k < 8; k++) {
      u32 pk = (u32)f2b(nba[k] - suma) | ((u32)f2b(nbb[k] - sumb) << 16);
      *(u32*)&Mb[(size_t)(128 + 256 * si + k * 32 + c) * HW + s] = pk;
    }
  }
}

// ------------ Gram via MFMA v6: parameterized ks split (ksb = log2 nks).
// Same proven loop body (32KB LDS, gload16 + XOR swizzle, diag dedup),
// non-atomic partials into Gpart[(b*nks+ks)][tile].
__global__ __launch_bounds__(256) void gram_mfma(
    const u16* __restrict__ Mbuf, float* __restrict__ Gpart, int ksb) {
  const int id = blockIdx.x;
  const int nks = 1 << ksb;
  const int tile = id >> (ksb + 1), combo = id & ((2 << ksb) - 1);
  const int ks = combo >> 1, b = combo & 1;
  int r0, c0, gstride; size_t goff;
  tile_decode(tile, r0, c0, goff, gstride);
  const bool diag = (r0 == c0);
  const u16* Mb = Mbuf + (size_t)b * 1152 * HW;
  __shared__ u16 As[128 * 64];   // 16 KB
  __shared__ u16 Bs[128 * 64];   // 16 KB
  const int t = threadIdx.x;
  const int lane = t & 63, w = t >> 6;
  const int wr = w >> 1, wc = w & 1;
  const int m = lane & 15, quad = lane >> 4;
  const int lr = lane >> 3;
  const int lsl = ((lane & 7) ^ (lr & 7)) * 8;   // pre-swizzled global k-slot
  const int klen = 16384 >> ksb;
  const int kbase = ks * klen;
  f32x4 acc[4][4];
  #pragma unroll
  for (int i = 0; i < 4; i++)
    #pragma unroll
    for (int j = 0; j < 4; j++) acc[i][j] = (f32x4){0.f, 0.f, 0.f, 0.f};

  for (int s0 = kbase; s0 < kbase + klen; s0 += 64) {
    #pragma unroll
    for (int q = 0; q < 4; q++) {
      const int R0 = w * 32 + q * 8;
      gload16(Mb + (size_t)(r0 + R0 + lr) * HW + s0 + lsl, &As[R0 * 64]);
    }
    if (!diag) {
      #pragma unroll
      for (int q = 0; q < 4; q++) {
        const int R0 = w * 32 + q * 8;
        gload16(Mb + (size_t)(c0 + R0 + lr) * HW + s0 + lsl, &Bs[R0 * 64]);
      }
    }
    __syncthreads();
    const u16* Bb = diag ? As : Bs;
    #pragma unroll
    for (int kh = 0; kh < 2; kh++) {
      short8 af[4], bf[4];
      const int slot = ((quad + 4 * kh) ^ (m & 7)) * 8;
      #pragma unroll
      for (int i = 0; i < 4; i++)
        af[i] = *(const short8*)&As[(wr * 64 + i * 16 + m) * 64 + slot];
      #pragma unroll
      for (int j = 0; j < 4; j++)
        bf[j] = *(const short8*)&Bb[(wc * 64 + j * 16 + m) * 64 + slot];
      #pragma unroll
      for (int i = 0; i < 4; i++)
        #pragma unroll
        for (int j = 0; j < 4; j++)
          acc[i][j] = __builtin_amdgcn_mfma_f32_16x16x32_bf16(af[i], bf[j], acc[i][j], 0, 0, 0);
    }
    __syncthreads();
  }
  float* Gb = Gpart + (size_t)(b * nks + ks) * GP_SLOT + (size_t)tile * 16384;
  #pragma unroll
  for (int i = 0; i < 4; i++)
    #pragma unroll
    for (int j = 0; j < 4; j++) {
      int col = wc * 64 + j * 16 + m;
      #pragma unroll
      for (int r = 0; r < 4; r++) {
        int row = wr * 64 + i * 16 + quad * 4 + r;
        Gb[row * 128 + col] = acc[i][j][r];
      }
    }
}

// ---- greduce: sum nks K-slices per tile (L3-resident) -> compact G.
__global__ __launch_bounds__(256) void greduce(
    const float* __restrict__ Gpart, float* __restrict__ G, int nks) {
  const int chunk = blockIdx.x, tile = blockIdx.y, b = blockIdx.z;
  int r0, c0, gstride; size_t goff;
  tile_decode(tile, r0, c0, goff, gstride);
  const int t = threadIdx.x;
  const int e = chunk * 1024 + t * 4;
  const float* base = Gpart + (size_t)b * nks * GP_SLOT + (size_t)tile * 16384 + e;
  f32x4 acc = *(const f32x4*)base;
  for (int s = 1; s < nks; s++) acc += *(const f32x4*)(base + (size_t)s * GP_SLOT);
  const int row = e >> 7, col = e & 127;
  *(f32x4*)&G[(size_t)b * G_SZ + goff + (size_t)row * gstride + col] = acc;
}

// ------------------------------------- mirror S_j lower-left = upper-right^T
__global__ __launch_bounds__(256) void mirror_S(float* __restrict__ G) {
  const int j = blockIdx.x & 3, b = blockIdx.x >> 2;
  float* base = G + (size_t)b * G_SZ + G_S + (size_t)j * 65536;
  const int t = threadIdx.x;
  for (int e = t; e < 16384; e += 256) {
    int rr = e >> 7, cc = e & 127;
    base[(size_t)(128 + rr) * 256 + cc] = base[(size_t)cc * 256 + 128 + rr];
  }
}

// ------------------------------------------------------------------ Q row inv-norms
__global__ __launch_bounds__(64) void qnorm(
    const u16* __restrict__ qw, const float* __restrict__ G,
    float* __restrict__ invQ) {
  const int bn = blockIdx.x, b = bn >> 2, n = bn & 3;
  const int rq = threadIdx.x;
  const int i = rq & 3, q1r = rq >> 2;
  const u16* qr = qw + ((size_t)(i * 64) + 16 * n + q1r) * 32;
  float v[32];
  #pragma unroll
  for (int c = 0; c < 32; c++) v[c] = b2f(qr[c]);
  const float* D1 = G + (size_t)b * G_SZ;
  float ss = 0.f;
  for (int c = 0; c < 32; c++) {
    float tmp = 0.f;
    #pragma unroll
    for (int c2 = 0; c2 < 32; c2++) tmp = fmaf(v[c2], D1[(size_t)(32 * i + c2) * 128 + 32 * i + c], tmp);
    ss = fmaf(tmp, v[c], ss);
  }
  invQ[bn * 64 + rq] = 1.f / fmaxf(sqrtf(fmaxf(ss, 0.f)), 1e-12f);
}

// ---- knorm v2: 8 K-rows (same j) per block; S_j read ONCE per block.
__global__ __launch_bounds__(256) void knorm(
    const u16* __restrict__ kw, const float* __restrict__ G,
    float* __restrict__ invK) {
  const int jj = blockIdx.x;          // 0..63
  const int j = jj & 3, kkg = jj >> 2;
  const int n = blockIdx.y, b = blockIdx.z;
  const int t = threadIdx.x;
  __shared__ float vs[8][256];        // 8 K-rows
  for (int e = t; e < 2048; e += 256) {
    int r = e >> 8, c = e & 255;
    vs[r][c] = b2f(kw[((size_t)(j * 512) + 128 * n + kkg * 8 + r) * 256 + c]);
  }
  __syncthreads();
  const float* S = G + (size_t)b * G_SZ + G_S + (size_t)j * 65536;
  float acc[8];
  #pragma unroll
  for (int r = 0; r < 8; r++) acc[r] = 0.f;
  for (int c2 = 0; c2 < 256; c2++) {
    float sv = S[(size_t)c2 * 256 + t];
    #pragma unroll
    for (int r = 0; r < 8; r++) acc[r] = fmaf(vs[r][c2], sv, acc[r]);
  }
  #pragma unroll
  for (int r = 0; r < 8; r++) acc[r] *= vs[r][t];
  __shared__ float red[8][4];
  const int wv = t >> 6, lane = t & 63;
  #pragma unroll
  for (int r = 0; r < 8; r++) {
    float v = wave_sum(acc[r]);
    if (lane == 0) red[r][wv] = v;
  }
  __syncthreads();
  if (t < 8) {
    float tot = fmaxf(red[t][0] + red[t][1] + red[t][2] + red[t][3], 0.f);
    invK[(size_t)(b * 4 + n) * 512 + 4 * (kkg * 8 + t) + j] =
        1.f / fmaxf(sqrtf(tot), 1e-12f);
  }
}

// ---------- score2 v3: KD = D2_j . kw_half^T, then q_w.KD; epilogue fuses
// iQ/iK/isc scaling + InstanceNorm partial stats (atomics into sstat).
__global__ __launch_bounds__(256) void score2(
    const u16* __restrict__ qw, const u16* __restrict__ kw,
    const float* __restrict__ G, const float* __restrict__ invQ,
    const float* __restrict__ invK, float* __restrict__ score,
    float* __restrict__ sstat) {
  const int jj = blockIdx.x;        // 0..7
  const int j = jj >> 1, half = jj & 1;
  const int n = blockIdx.y, b = blockIdx.z;
  const float* D2 = G + (size_t)b * G_SZ + G_D2;
  const u16* kwb = kw + ((size_t)(j * 512) + 128 * n + half * 64) * 256;  // 64 rows
  __shared__ float As[64][132];
  __shared__ u16 Bs[64][68];
  __shared__ float KD[128][68];
  __shared__ float qws[64][32];
  const int t = threadIdx.x;
  const int tx = t & 7, ty = t >> 3;
  float acc[4][8];
  #pragma unroll
  for (int i = 0; i < 4; i++)
    #pragma unroll
    for (int u = 0; u < 8; u++) acc[i][u] = 0.f;
  for (int ch0 = 0; ch0 < 256; ch0 += 64) {
    for (int e = t; e < 8192; e += 256) {
      int r = e >> 6, kc = e & 63;
      As[kc][r] = D2[(size_t)r * 1024 + j * 256 + ch0 + kc];
    }
    for (int e = t; e < 4096; e += 256) {
      int r = e >> 6, kc = e & 63;
      Bs[kc][r] = kwb[(size_t)r * 256 + ch0 + kc];
    }
    __syncthreads();
    #pragma unroll 4
    for (int kc = 0; kc < 64; kc++) {
      float a[4];
      #pragma unroll
      for (int i = 0; i < 4; i++) a[i] = As[kc][ty * 4 + i];
      float bb[8];
      #pragma unroll
      for (int u = 0; u < 8; u++) bb[u] = b2f(Bs[kc][tx * 8 + u]);
      #pragma unroll
      for (int i = 0; i < 4; i++)
        #pragma unroll
        for (int u = 0; u < 8; u++) acc[i][u] = fmaf(a[i], bb[u], acc[i][u]);
    }
    __syncthreads();
  }
  #pragma unroll
  for (int i = 0; i < 4; i++)
    #pragma unroll
    for (int u = 0; u < 8; u++) KD[ty * 4 + i][tx * 8 + u] = acc[i][u];
  for (int e = t; e < 2048; e += 256) {
    int q = e >> 5, c = e & 31;
    int i = q & 3, q1r = q >> 2;
    qws[q][c] = b2f(qw[((size_t)(i * 64) + 16 * n + q1r) * 32 + c]);
  }
  __syncthreads();
  const int bn = b * 4 + n;
  float* sb = score + (size_t)bn * 64 * 512;
  const float* iQ = invQ + bn * 64;
  const float* iK = invK + (size_t)bn * 512;
  const float isc = 1.f / 128.f;
  float lsum = 0.f, lss = 0.f;
  for (int e = t; e < 4096; e += 256) {
    int q = e >> 6, kkl = e & 63;
    int i = q & 3;
    float s = 0.f;
    #pragma unroll
    for (int c = 0; c < 32; c++) s = fmaf(qws[q][c], KD[i * 32 + c][kkl], s);
    int col = 4 * (half * 64 + kkl) + j;
    float v = s * iQ[q] * iK[col] * isc;
    sb[(size_t)q * 512 + col] = v;
    lsum += v; lss += v * v;
  }
  lsum = wave_sum(lsum); lss = wave_sum(lss);
  __shared__ float redp[8];
  if ((t & 63) == 0) { redp[t >> 6] = lsum; redp[4 + (t >> 6)] = lss; }
  __syncthreads();
  if (t == 0) {
    atomicAdd(&sstat[bn * 2],     redp[0] + redp[1] + redp[2] + redp[3]);
    atomicAdd(&sstat[bn * 2 + 1], redp[4] + redp[5] + redp[6] + redp[7]);
  }
}

// ------- in_softmax v2: normalize + row softmax only (stats precomputed);
__global__ __launch_bounds__(256) void in_softmax(
    float* __restrict__ score, const float* __restrict__ sstat) {
  const int bn = blockIdx.y, rg = blockIdx.x;
  float* sb = score + (size_t)bn * 64 * 512;
  const int t = threadIdx.x;
  float mean = sstat[bn * 2] * (1.f / 32768.f);
  float var = sstat[bn * 2 + 1] * (1.f / 32768.f) - mean * mean;
  float istd = rsqrtf(var + 1e-5f);
  const int wv = t >> 6, lane = t & 63;
  for (int rr = wv; rr < 8; rr += 4) {
    int r = rg * 8 + rr;
    float z[8];
    float m = -1e30f;
    #pragma unroll
    for (int jx = 0; jx < 8; jx++) {
      z[jx] = (sb[(size_t)r * 512 + lane + 64 * jx] - mean) * istd;
      m = fmaxf(m, z[jx]);
    }
    m = wave_max(m);
    float sloc = 0.f;
    #pragma unroll
    for (int jx = 0; jx < 8; jx++) { z[jx] = expf(z[jx] - m); sloc += z[jx]; }
    sloc = wave_sum(sloc);
    float rinv = 1.f / sloc;
    #pragma unroll
    for (int jx = 0; jx < 8; jx++) sb[(size_t)r * 512 + lane + 64 * jx] = z[jx] * rinv;
  }
}

// --------- attnW2 v2: grid (j*4+n, q0, b); thread = out channel; coalesced vw reads
__global__ __launch_bounds__(256) void attnW2(
    const float* __restrict__ attn, const u16* __restrict__ vw,
    float* __restrict__ W2) {
  const int j = blockIdx.x >> 2, n = blockIdx.x & 3;
  const int q0 = blockIdx.y * 8, b = blockIdx.z, bn = b * 4 + n;
  const float* ab = attn + (size_t)bn * 64 * 512;
  const int t = threadIdx.x;  // = ch 0..255
  __shared__ float at_s[8][128];
  for (int e = t; e < 1024; e += 256) {
    int qg = e >> 7, kk = e & 127;
    at_s[qg][kk] = ab[(size_t)(q0 + qg) * 512 + 4 * kk + j];
  }
  __syncthreads();
  float acc[8];
  #pragma unroll
  for (int qg = 0; qg < 8; qg++) acc[qg] = 0.f;
  const u16* vcol = vw + ((size_t)(j * 512) + 128 * n) * 256 + t;
  for (int kk = 0; kk < 128; kk++) {
    float v = b2f(vcol[(size_t)kk * 256]);
    #pragma unroll
    for (int qg = 0; qg < 8; qg++) acc[qg] = fmaf(at_s[qg][kk], v, acc[qg]);
  }
  #pragma unroll
  for (int qg = 0; qg < 8; qg++)
    W2[((size_t)bn * 64 + q0 + qg) * 1024 + j * 256 + t] = acc[qg];
}

// ---- wfin v2: Wfin16[b][o][jc] = bf16(out_w . W2). Block = (jc-tile 256,
// o-tile 16, b). Coalesced W2 column reads (lane = jc), ow rows LDS-broadcast.
__global__ __launch_bounds__(256) void wfin_k(
    const u16* __restrict__ ow, const float* __restrict__ W2,
    u16* __restrict__ Wfin16) {
  const int jc0 = blockIdx.x * 256;
  const int o0 = blockIdx.y * 16;
  const int b = blockIdx.z;
  __shared__ float ows[16][257];
  const int t = threadIdx.x;
  for (int e = t; e < 4096; e += 256) {
    int o = e >> 8, c = e & 255;
    ows[o][c] = b2f(ow[(size_t)(o0 + o) * 256 + c]);
  }
  __syncthreads();
  const float* W2b = W2 + (size_t)b * 256 * 1024 + jc0 + t;
  float acc[16];
  #pragma unroll
  for (int o = 0; o < 16; o++) acc[o] = 0.f;
  for (int c = 0; c < 256; c++) {
    float w2v = W2b[(size_t)c * 1024];
    #pragma unroll
    for (int o = 0; o < 16; o++) acc[o] = fmaf(ows[o][c], w2v, acc[o]);
  }
  u16* dst = Wfin16 + (size_t)b * 256 * 1024 + jc0 + t;
  #pragma unroll
  for (int o = 0; o < 16; o++)
    dst[(size_t)(o0 + o) * 1024] = f2b(acc[o]);
}

// ----- y_gemm v6: dbuf single-barrier pipeline; A via global_load_lds(16B)
// +XOR swizzle; B reg-transpose with STATIC indices into 3-term-XOR LDS
// layout: slot(chunk,row) = chunk ^ (row&7) ^ ((row>>3)&7).
__global__ __launch_bounds__(256) void y_gemm_mfma(
    const u16* __restrict__ Wfin16, const u16* __restrict__ Mbuf,
    u16* __restrict__ ybuf) {
  const int b = blockIdx.y, col0 = blockIdx.x * 64;
  __shared__ u16 As[2][256 * 64];  // 64 KB  [o-row][k-slot swizzled: c^(r&7)]
  __shared__ u16 Bs[2][64 * 64];   // 16 KB  [s-col][k-slot swizzled: c^(r&7)^(r>>3)]
  const u16* Ab = Wfin16 + (size_t)b * 256 * 1024;
  const u16* Mb = Mbuf + (size_t)b * 1152 * HW + (size_t)128 * HW;
  const int t = threadIdx.x;
  const int lane = t & 63, w = t >> 6;
  const int m = lane & 15, quad = lane >> 4;
  const int kp = t >> 3, cs = t & 7;           // B: k-pair 0..31, s-chunk 0..7
  const int lr = lane >> 3;                    // A staging: row within 8-group
  const int lsl = ((lane & 7) ^ (lr & 7)) * 8; // pre-swizzled global k-slot
  f32x4 acc[4][4];
  #pragma unroll
  for (int i = 0; i < 4; i++)
    #pragma unroll
    for (int j = 0; j < 4; j++) acc[i][j] = (f32x4){0.f, 0.f, 0.f, 0.f};

  uint4 v0, v1;
  auto stageA = [&](int buf, int k0c) {
    #pragma unroll
    for (int q = 0; q < 8; q++)
      gload16(&Ab[(size_t)(w * 64 + q * 8 + lr) * 1024 + k0c + lsl],
              &As[buf][(w * 64 + q * 8) * 64]);
  };
  auto loadB = [&](int k0c) {
    v0 = *(const uint4*)&Mb[(size_t)(k0c + 2 * kp) * HW + col0 + cs * 8];
    v1 = *(const uint4*)&Mb[(size_t)(k0c + 2 * kp + 1) * HW + col0 + cs * 8];
  };
  auto writeB = [&](int buf) {
    u16 t0[8], t1[8];
    *(uint4*)t0 = v0; *(uint4*)t1 = v1;
    const int ksl = kp >> 2, kin = (2 * kp) & 7;
    #pragma unroll
    for (int uu = 0; uu < 8; uu++) {        // STATIC index — registers
      int r = cs * 8 + uu;                  // r&7 = uu, r>>3 = cs
      u32 pair = (u32)t0[uu] | ((u32)t1[uu] << 16);
      *(u32*)&Bs[buf][r * 64 + (((ksl ^ uu ^ cs) & 7) << 3) + kin] = pair;
    }
  };

  stageA(0, 0);
  loadB(0);
  writeB(0);
  __syncthreads();

  int cur = 0;
  for (int step = 0; step < 16; step++) {
    const int nxt = cur ^ 1;
    if (step < 15) {
      stageA(nxt, (step + 1) * 64);
      loadB((step + 1) * 64);
    }
    #pragma unroll
    for (int kh = 0; kh < 2; kh++) {
      short8 af[4], bf[4];
      const int slotA = ((4 * kh + quad) ^ (m & 7)) * 8;
      #pragma unroll
      for (int i = 0; i < 4; i++)
        af[i] = *(const short8*)&As[cur][(w * 64 + i * 16 + m) * 64 + slotA];
      #pragma unroll
      for (int j = 0; j < 4; j++) {
        const int row = j * 16 + m;
        const int slotB = (((4 * kh + quad) ^ (row & 7) ^ ((row >> 3) & 7)) & 7) * 8;
        bf[j] = *(const short8*)&Bs[cur][row * 64 + slotB];
      }
      #pragma unroll
      for (int i = 0; i < 4; i++)
        #pragma unroll
        for (int j = 0; j < 4; j++)
          acc[i][j] = __builtin_amdgcn_mfma_f32_16x16x32_bf16(af[i], bf[j], acc[i][j], 0, 0, 0);
    }
    if (step < 15) {
      writeB(nxt);
      __syncthreads();
      cur = nxt;
    }
  }
  #pragma unroll
  for (int i = 0; i < 4; i++)
    #pragma unroll
    for (int j = 0; j < 4; j++) {
      int col = col0 + j * 16 + m;
      #pragma unroll
      for (int r = 0; r < 4; r++) {
        int row = w * 64 + i * 16 + quad * 4 + r;
        ybuf[((size_t)b * 256 + row) * HW + col] = f2b(acc[i][j][r]);
      }
    }
}

// ---------------------------------------------------------------- BatchNorm
__global__ __launch_bounds__(256) void bn_stats(
    const u16* __restrict__ y, float* __restrict__ st) {
  const int o = blockIdx.x;
  const int t = threadIdx.x;
  float sum = 0.f, ss = 0.f;
  for (int bb = 0; bb < 2; bb++) {
    const u16* p = y + ((size_t)bb * 256 + o) * HW;
    for (int e = t; e < HW / 8; e += 256) {
      uint4 v = ((const uint4*)p)[e];
      float f[8];
      unpack8(v, f);
      #pragma unroll
      for (int k = 0; k < 8; k++) { sum += f[k]; ss += f[k] * f[k]; }
    }
  }
  __shared__ float red[8];
  sum = wave_sum(sum); ss = wave_sum(ss);
  if ((t & 63) == 0) { red[t >> 6] = sum; red[4 + (t >> 6)] = ss; }
  __syncthreads();
  if (t == 0) {
    float mean = (red[0] + red[1] + red[2] + red[3]) / 32768.f;
    float var = (red[4] + red[5] + red[6] + red[7]) / 32768.f - mean * mean;
    st[o * 2] = mean;
    st[o * 2 + 1] = rsqrtf(var + 1e-5f);
  }
}

__global__ __launch_bounds__(256) void bn_apply(
    const u16* __restrict__ y, const float* __restrict__ st,
    const u16* __restrict__ gamma, const u16* __restrict__ beta,
    const int* __restrict__ flag, void* __restrict__ out) {
  const int idx8 = blockIdx.x * 256 + threadIdx.x;
  const int r = idx8 >> 11;
  const int o = r & 255;
  float mean = st[o * 2], istd = st[o * 2 + 1];
  float g = b2f(gamma[o]), be = b2f(beta[o]);
  uint4 v = ((const uint4*)y)[idx8];
  float f[8];
  unpack8(v, f);
  float rr[8];
  #pragma unroll
  for (int k = 0; k < 8; k++) rr[k] = fmaxf((f[k] - mean) * istd * g + be, 0.f);
  if (*flag) {
    float* of = (float*)out + (size_t)idx8 * 8;
    *(float4*)of = make_float4(rr[0], rr[1], rr[2], rr[3]);
    *(float4*)(of + 4) = make_float4(rr[4], rr[5], rr[6], rr[7]);
  } else {
    u32 p0 = (u32)f2b(rr[0]) | ((u32)f2b(rr[1]) << 16);
    u32 p1 = (u32)f2b(rr[2]) | ((u32)f2b(rr[3]) << 16);
    u32 p2 = (u32)f2b(rr[4]) | ((u32)f2b(rr[5]) << 16);
    u32 p3 = (u32)f2b(rr[6]) | ((u32)f2b(rr[7]) << 16);
    ((uint4*)out)[idx8] = make_uint4(p0, p1, p2, p3);
  }
}

// ----------------------------------------------------------------------------
extern "C" void kernel_launch(void* const* d_in, const int* in_sizes, int n_in,
                              void* d_out, int out_size, void* d_ws, size_t ws_size,
                              hipStream_t stream) {
  float* G     = (float*)d_ws;           // 819,200 f32 (2 x G_SZ)
  float* score = G + 819200;             // 262,144
  float* invQ  = score + 262144;         // 512
  float* invK  = invQ + 512;             // 4,096
  float* W2    = invK + 4096;            // 524,288
  float* Wfin  = W2 + 524288;            // slot reused: u16 Wfin16
  float* bnst  = Wfin + 524288;          // 512
  float* sstat = bnst + 512;             // 16 (IN stats) + 16 zero-page
  float* zbuf  = sstat + 16;             // 64 B zeros (edge-px gload source)
  int* flag    = (int*)(zbuf + 16);      // 16
  u16* Sbuf    = (u16*)(flag + 16);      // S_TOTAL u16
  u16* Mbuf    = Sbuf + S_TOTAL;         // 37,748,736 u16
  u16* ybuf    = Mbuf + 37748736;        // 8,388,608 u16 (16 MB)
  u16* Wfin16  = (u16*)Wfin;
  float* lgbuf = (float*)ybuf;           // alias: 4 MB [z][s][8], dead before gram
  u16* cenT    = (u16*)(lgbuf + 1048576);// alias: 2 MB [b][s][ci], dead before gram
  float* Gpart = (float*)ybuf;           // alias: partial-G; dead after greduce

  // ks split: 32 if workspace allows 2*32 slots (88 MB at Gpart), else 16.
  const size_t gp_off = (size_t)((char*)Gpart - (char*)d_ws);
  const int ksb = (ws_size >= gp_off + 2ull * 32 * GP_SLOT * 4) ? 5 : 4;

  probe<<<1, 64, 0, stream>>>((const u32*)d_in[10], flag);
  convert_all<<<dim3(1024, 1, 12), 256, 0, stream>>>(
      d_in[0], d_in[1], d_in[2], d_in[3], d_in[4], d_in[5], d_in[6], d_in[7],
      d_in[8], d_in[9], d_in[10], d_in[11], Sbuf, flag);
  hipMemsetAsync(sstat, 0, 32 * sizeof(float), stream);  // sstat + zbuf

  transp<<<dim3(64, 2), 256, 0, stream>>>(Sbuf + S_CEN, cenT);
  sur_w<<<dim3(128, 8), 256, 0, stream>>>(
      cenT, Sbuf + S_W1, Sbuf + S_B1, Sbuf + S_W2, (const u16*)zbuf, lgbuf);
  sur_scatter<<<dim3(32, 4, 8), 256, 0, stream>>>(
      Sbuf + S_CEN, lgbuf, Sbuf + S_B2, Sbuf + S_SW, Mbuf);
  gram_mfma<<<21 << (ksb + 1), 256, 0, stream>>>(Mbuf, Gpart, ksb);
  greduce<<<dim3(16, 21, 2), 256, 0, stream>>>(Gpart, G, 1 << ksb);
  mirror_S<<<8, 256, 0, stream>>>(G);
  qnorm<<<8, 64, 0, stream>>>(Sbuf + S_QW, G, invQ);
  knorm<<<dim3(64, 4, 2), 256, 0, stream>>>(Sbuf + S_KW, G, invK);
  score2<<<dim3(8, 4, 2), 256, 0, stream>>>(
      Sbuf + S_QW, Sbuf + S_KW, G, invQ, invK, score, sstat);
  in_softmax<<<dim3(8, 8), 256, 0, stream>>>(score, sstat);
  attnW2<<<dim3(16, 8, 2), 256, 0, stream>>>(score, Sbuf + S_VW, W2);
  wfin_k<<<dim3(4, 16, 2), 256, 0, stream>>>(Sbuf + S_OW, W2, Wfin16);
  y_gemm_mfma<<<dim3(256, 2), 256, 0, stream>>>(Wfin16, Mbuf, ybuf);
  bn_stats<<<256, 256, 0, stream>>>(ybuf, bnst);
  bn_apply<<<4096, 256, 0, stream>>>(ybuf, bnst, Sbuf + S_GAMMA, Sbuf + S_BETA,
                                     flag, d_out);
}

// Round 12
// 349.873 us; speedup vs baseline: 1.0952x; 1.0952x over previous
//
#include <hip/hip_runtime.h>

// Gram-trick + MFMA. Ladder: 2310 -> ... -> 462 -> 392 -> (425) -> 363 -> (384) -> 351 -> 352 -> (383).
// R24: REVERT ks split to 16 (R23's ks=32 flipped gram HBM-bound: 88MB Gpart
// writes evicted Mbuf panels from L3, FETCH 41->104MB, 3.3TB/s = exactly the
// 59us measured). Back to the proven R22 operating point; ksb stays a param.

#define HW 16384
typedef unsigned short u16;
typedef unsigned int u32;
typedef __attribute__((ext_vector_type(8))) short short8;
typedef __attribute__((ext_vector_type(4))) float f32x4;

// staging offsets (u16 elements)
#define S_CEN 0
#define S_QW 1048576
#define S_KW 1056768
#define S_VW 1581056
#define S_W1 2105344
#define S_B1 2142208
#define S_W2 2142336
#define S_B2 2143360
#define S_SW 2143392
#define S_OW 2143400
#define S_GAMMA 2208936
#define S_BETA 2209192
#define S_TOTAL 2209456

// compact Gram layout per batch (f32 elements)
#define G_D1 0       // 128x128, stride 128
#define G_D2 16384   // 128x1024, stride 1024
#define G_S 147456   // 4 blocks of 256x256, stride 256
#define G_SZ 409600

// partial-G: 21 tiles x 16384 per (b,ks) slot
#define GP_SLOT 344064

__device__ __forceinline__ float b2f(u16 u) { return __uint_as_float(((u32)u) << 16); }
__device__ __forceinline__ u16 f2b(float f) {
  u32 u = __float_as_uint(f);
  return (u16)((u + 0x7FFFu + ((u >> 16) & 1u)) >> 16);  // RNE
}
__device__ __forceinline__ float wave_sum(float v) {
  #pragma unroll
  for (int off = 32; off > 0; off >>= 1) v += __shfl_xor(v, off, 64);
  return v;
}
__device__ __forceinline__ float wave_max(float v) {
  #pragma unroll
  for (int off = 32; off > 0; off >>= 1) v = fmaxf(v, __shfl_xor(v, off, 64));
  return v;
}
__device__ __forceinline__ void unpack8(uint4 v, float* f) {
  f[0] = __uint_as_float(v.x << 16); f[1] = __uint_as_float(v.x & 0xFFFF0000u);
  f[2] = __uint_as_float(v.y << 16); f[3] = __uint_as_float(v.y & 0xFFFF0000u);
  f[4] = __uint_as_float(v.z << 16); f[5] = __uint_as_float(v.z & 0xFFFF0000u);
  f[6] = __uint_as_float(v.w << 16); f[7] = __uint_as_float(v.w & 0xFFFF0000u);
}
__device__ __forceinline__ void gload16(const u16* g, u16* l) {
  __builtin_amdgcn_global_load_lds(
      (const __attribute__((address_space(1))) void*)g,
      (__attribute__((address_space(3))) void*)l, 16, 0, 0);
}

// tile -> (r0, c0, goff, gstride) decode, shared by gram_mfma / greduce
__device__ __forceinline__ void tile_decode(int tile, int& r0, int& c0,
                                            size_t& goff, int& gstride) {
  if (tile == 0) { r0 = 0; c0 = 0; goff = G_D1; gstride = 128; }
  else if (tile < 9) { r0 = 0; c0 = 128 * tile; goff = G_D2 + (size_t)(tile - 1) * 128; gstride = 1024; }
  else if (tile < 17) {
    int t2 = tile - 9; int j = t2 >> 1, p = t2 & 1;
    r0 = 128 + 256 * j + 128 * p; c0 = r0;
    goff = G_S + (size_t)j * 65536 + (size_t)p * (128 * 256 + 128); gstride = 256;
  } else {
    int j = tile - 17;
    r0 = 128 + 256 * j; c0 = r0 + 128;
    goff = G_S + (size_t)j * 65536 + 128; gstride = 256;
  }
}

// ------------------------------------------------------------ dtype probe
__global__ void probe(const u32* __restrict__ g, int* __restrict__ flag) {
  if (threadIdx.x == 0) {
    int ok = 1;
    #pragma unroll
    for (int i = 0; i < 4; i++) {
      u32 w = g[i];
      u32 lo = w & 0xFFFFu, hi = w >> 16;
      ok &= (lo >= 0x3E00u && lo <= 0x4100u) ? 1 : 0;
      ok &= (hi >= 0x3E00u && hi <= 0x4100u) ? 1 : 0;
    }
    *flag = ok ? 0 : 1;  // 0 = bf16 inputs, 1 = f32 inputs
  }
}

// ------------------------------------------------------------ stage inputs -> bf16
__global__ __launch_bounds__(256) void convert_all(
    const void* p0, const void* p1, const void* p2, const void* p3,
    const void* p4, const void* p5, const void* p6, const void* p7,
    const void* p8, const void* p9, const void* p10, const void* p11,
    u16* __restrict__ S, const int* __restrict__ flag) {
  const void* src; int n; int off;
  switch (blockIdx.z) {
    case 0:  src = p0;  n = 1048576; off = S_CEN; break;
    case 1:  src = p1;  n = 8192;    off = S_QW; break;
    case 2:  src = p2;  n = 524288;  off = S_KW; break;
    case 3:  src = p3;  n = 524288;  off = S_VW; break;
    case 4:  src = p4;  n = 36864;   off = S_W1; break;
    case 5:  src = p5;  n = 128;     off = S_B1; break;
    case 6:  src = p6;  n = 1024;    off = S_W2; break;
    case 7:  src = p7;  n = 32;      off = S_B2; break;
    case 8:  src = p8;  n = 8;       off = S_SW; break;
    case 9:  src = p9;  n = 65536;   off = S_OW; break;
    case 10: src = p10; n = 256;     off = S_GAMMA; break;
    default: src = p11; n = 256;     off = S_BETA; break;
  }
  int idx = (blockIdx.x * 256 + threadIdx.x) * 4;
  if (idx >= n) return;
  u16* dst = S + off + idx;
  if (*flag) {
    float4 v = ((const float4*)src)[idx >> 2];
    dst[0] = f2b(v.x); dst[1] = f2b(v.y); dst[2] = f2b(v.z); dst[3] = f2b(v.w);
  } else {
    *(ushort4*)dst = ((const ushort4*)src)[idx >> 2];
  }
}

// ---- transp: cen[b][ci][s] -> cenT[b][s][ci]  (LDS-tiled, 2 MB total)
__global__ __launch_bounds__(256) void transp(
    const u16* __restrict__ cen, u16* __restrict__ cenT) {
  __shared__ u16 tile[32][258];
  const int t = threadIdx.x;
  const int s0 = blockIdx.x * 256;
  const u16* cb = cen + (size_t)blockIdx.y * 32 * HW;
  for (int e = t; e < 2048; e += 256) {
    int ci = e >> 6, sx = (e & 63) * 4;
    *(u32*)&tile[ci][sx] = *(const u32*)&cb[(size_t)ci * HW + s0 + sx];
    *(u32*)&tile[ci][sx + 2] = *(const u32*)&cb[(size_t)ci * HW + s0 + sx + 2];
  }
  __syncthreads();
  u16* ob = cenT + (size_t)blockIdx.y * HW * 32;
  for (int e = t; e < 1024; e += 256) {
    int px = e >> 2, cg = (e & 3) * 8;
    u16 tmp[8];
    #pragma unroll
    for (int k = 0; k < 8; k++) tmp[k] = tile[cg + k][px];
    *(uint4*)&ob[(size_t)(s0 + px) * 32 + cg] = *(uint4*)tmp;
  }
}

// --- sur_w v9: conv via MFMA im2col. Block = 1 image row (128 px), one z.
__global__ __launch_bounds__(256) void sur_w(
    const u16* __restrict__ cenT, const u16* __restrict__ w1g,
    const u16* __restrict__ b1g, const u16* __restrict__ w2g,
    const u16* __restrict__ zbuf, float* __restrict__ lgbuf) {
  const int z = blockIdx.y;            // b*4+si
  const int b = z >> 2, si = z & 3, d = 1 << si;
  const int hh = blockIdx.x;           // image row 0..127
  __shared__ __align__(16) char smem[27776];
  u16* Bs = (u16*)smem;                // 8 KB   [128 px][32 ci] (chunk-swizzled)
  u16* w1s = (u16*)(smem + 8192);      // 18 KB  [9][32 co][32 ci] (chunk-swizzled)
  float* h1s = (float*)smem;           // 16.9 KB [128][33], aliases Bs/w1s post-taps
  __shared__ float w2s[8][32];
  __shared__ float b1s[32];
  const int t = threadIdx.x;
  for (int e = t; e < 9216; e += 256) {
    int tap = e >> 10, rem = e & 1023, co = rem >> 5, ci = rem & 31;
    int dst = tap * 1024 + co * 32 + ((((ci >> 3) ^ (co & 3)) << 3) | (ci & 7));
    w1s[dst] = w1g[si * 9216 + co * 288 + ci * 9 + tap];
  }
  w2s[t >> 5][t & 31] = b2f(w2g[si * 256 + t]);
  if (t < 32) b1s[t] = b2f(b1g[si * 32 + t]);

  const u16* cb = cenT + (size_t)b * HW * 32;
  const int lane = t & 63, w = t >> 6;
  const int m = lane & 15, quad = lane >> 4;
  const int slot8 = (quad ^ (m & 3)) << 3;   // swizzled k-chunk for frag reads
  f32x4 acc[2][2];
  #pragma unroll
  for (int i = 0; i < 2; i++)
    #pragma unroll
    for (int j = 0; j < 2; j++) acc[i][j] = (f32x4){0.f, 0.f, 0.f, 0.f};

  for (int tap = 0; tap < 9; tap++) {
    const int ky = tap / 3, kx = tap - ky * 3;
    const int y = hh + (ky - 1) * d;
    if (y < 0 || y > 127) continue;          // uniform: zero contribution
    const int dx = (kx - 1) * d;
    #pragma unroll
    for (int q = 0; q < 2; q++) {
      const int e = q * 256 + t;
      const int px = e >> 2, ck = e & 3;
      const int x = px + dx;
      const u16* src = ((unsigned)x < 128u)
          ? cb + ((size_t)(y * 128 + x) * 32 + ((ck ^ (px & 3)) << 3))
          : zbuf;
      gload16(src, Bs + (size_t)e * 8);
    }
    __syncthreads();
    short8 af[2], bf[2];
    #pragma unroll
    for (int i = 0; i < 2; i++)
      af[i] = *(const short8*)&Bs[(w * 32 + i * 16 + m) * 32 + slot8];
    #pragma unroll
    for (int j = 0; j < 2; j++)
      bf[j] = *(const short8*)&w1s[tap * 1024 + (j * 16 + m) * 32 + slot8];
    #pragma unroll
    for (int i = 0; i < 2; i++)
      #pragma unroll
      for (int j = 0; j < 2; j++)
        acc[i][j] = __builtin_amdgcn_mfma_f32_16x16x32_bf16(af[i], bf[j], acc[i][j], 0, 0, 0);
    __syncthreads();
  }

  #pragma unroll
  for (int i = 0; i < 2; i++)
    #pragma unroll
    for (int j = 0; j < 2; j++) {
      const int co = j * 16 + m;
      #pragma unroll
      for (int r = 0; r < 4; r++) {
        const int px = w * 32 + i * 16 + quad * 4 + r;
        h1s[px * 33 + co] = fmaxf(acc[i][j][r] + b1s[co], 0.f);
      }
    }
  __syncthreads();

  const int px = t >> 1, half = t & 1;
  float lp[4];
  #pragma unroll
  for (int k = 0; k < 4; k++) lp[k] = 0.f;
  #pragma unroll
  for (int i = 0; i < 32; i++) {
    const float v = h1s[px * 33 + i];
    #pragma unroll
    for (int k = 0; k < 4; k++) lp[k] = fmaf(v, w2s[half * 4 + k][i], lp[k]);
  }
  float* dst = lgbuf + ((size_t)z * HW + hh * 128 + px) * 8 + half * 4;
  *(float4*)dst = make_float4(lp[0], lp[1], lp[2], lp[3]);
}

// --- sur_scatter v4: read full logits [z][s][8], softmax, neighbors + sur writes
__global__ __launch_bounds__(256) void sur_scatter(
    const u16* __restrict__ cen, const float* __restrict__ lgbuf,
    const u16* __restrict__ b2g, const u16* __restrict__ swg,
    u16* __restrict__ Mbuf) {
  const int z = blockIdx.z;
  const int b = z >> 2, si = z & 3, d = 1 << si;
  const int c0 = blockIdx.y * 8;
  const int t = threadIdx.x;
  const int s = (blockIdx.x * 256 + t) * 2;  // even
  const int h = s >> 7, w = s & 127;

  float s0 = b2f(swg[si * 2 + 0]), s1 = b2f(swg[si * 2 + 1]);
  float mx = fmaxf(s0, s1);
  float e0 = expf(s0 - mx), e1 = expf(s1 - mx);
  float w20 = e0 / (e0 + e1), w21 = e1 / (e0 + e1);

  float b2s[8];
  #pragma unroll
  for (int k = 0; k < 8; k++) b2s[k] = b2f(b2g[si * 8 + k]);

  const float* lpa = lgbuf + ((size_t)z * HW + s) * 8;
  float lga[8], lgb[8];
  {
    float4 a0 = *(const float4*)lpa,       a1 = *(const float4*)(lpa + 4);
    float4 g0 = *(const float4*)(lpa + 8), g1 = *(const float4*)(lpa + 12);
    lga[0] = a0.x; lga[1] = a0.y; lga[2] = a0.z; lga[3] = a0.w;
    lga[4] = a1.x; lga[5] = a1.y; lga[6] = a1.z; lga[7] = a1.w;
    lgb[0] = g0.x; lgb[1] = g0.y; lgb[2] = g0.z; lgb[3] = g0.w;
    lgb[4] = g1.x; lgb[5] = g1.y; lgb[6] = g1.z; lgb[7] = g1.w;
  }
  {
    #pragma unroll
    for (int k = 0; k < 8; k++) lga[k] += b2s[k];
    float lm = lga[0];
    #pragma unroll
    for (int k = 1; k < 8; k++) lm = fmaxf(lm, lga[k]);
    float ls = 0.f;
    #pragma unroll
    for (int k = 0; k < 8; k++) { lga[k] = expf(lga[k] - lm); ls += lga[k]; }
    float inv = w20 / ls;
    #pragma unroll
    for (int k = 0; k < 8; k++) lga[k] *= inv;
  }
  {
    #pragma unroll
    for (int k = 0; k < 8; k++) lgb[k] += b2s[k];
    float lm = lgb[0];
    #pragma unroll
    for (int k = 1; k < 8; k++) lm = fmaxf(lm, lgb[k]);
    float ls = 0.f;
    #pragma unroll
    for (int k = 0; k < 8; k++) { lgb[k] = expf(lgb[k] - lm); ls += lgb[k]; }
    float inv = w20 / ls;
    #pragma unroll
    for (int k = 0; k < 8; k++) lgb[k] *= inv;
  }

  const int dy[8] = {-d, -d, -d, 0, 0, d, d, d};
  const int dx[8] = {-d, 0, d, -d, d, -d, 0, d};
  int offa[8], offb[8];
  #pragma unroll
  for (int k = 0; k < 8; k++) {
    int y = h + dy[k]; y = y < 0 ? -y : (y > 127 ? 254 - y : y);
    int xa = w + dx[k]; xa = xa < 0 ? -xa : (xa > 127 ? 254 - xa : xa);
    int xb = w + 1 + dx[k]; xb = xb < 0 ? -xb : (xb > 127 ? 254 - xb : xb);
    offa[k] = y * 128 + xa;
    offb[k] = y * 128 + xb;
  }
  const u16* cb = cen + (size_t)b * 32 * HW;
  u16* Mb = Mbuf + (size_t)b * 1152 * HW;
  for (int c = c0; c < c0 + 8; c++) {
    const u16* cc = cb + (size_t)c * HW;
    u32 cvp = *(const u32*)&cc[s];
    float cva = __uint_as_float(cvp << 16), cvb = __uint_as_float(cvp & 0xFFFF0000u);
    float nba[8], nbb[8];
    #pragma unroll
    for (int k = 0; k < 8; k++) { nba[k] = b2f(cc[offa[k]]); nbb[k] = b2f(cc[offb[k]]); }
    float sxa = 0.f, mna = 0.f, sxb = 0.f, mnb = 0.f;
    #pragma unroll
    for (int k = 0; k < 8; k++) {
      sxa = fmaf(lga[k], nba[k], sxa); mna += nba[k];
      sxb = fmaf(lgb[k], nbb[k], sxb); mnb += nbb[k];
    }
    float suma = sxa + cva * w21, sumb = sxb + cvb * w21;
    u32 cx = (u32)f2b(mna * 0.125f * w20 + cva * w21) |
             ((u32)f2b(mnb * 0.125f * w20 + cvb * w21) << 16);
    *(u32*)&Mb[(size_t)(32 * si + c) * HW + s] = cx;
    #pragma unroll
    for (int k = 0; k < 8; k++) {
      u32 pk = (u32)f2b(nba[k] - suma) | ((u32)f2b(nbb[k] - sumb) << 16);
      *(u32*)&Mb[(size_t)(128 + 256 * si + k * 32 + c) * HW + s] = pk;
    }
  }
}

// ------------ Gram via MFMA: parameterized ks split (ksb = log2 nks).
// Proven loop body (32KB LDS, gload16 + XOR swizzle, diag dedup),
// non-atomic partials into Gpart[(b*nks+ks)][tile]. ksb=4 operating point.
__global__ __launch_bounds__(256) void gram_mfma(
    const u16* __restrict__ Mbuf, float* __restrict__ Gpart, int ksb) {
  const int id = blockIdx.x;
  const int nks = 1 << ksb;
  const int tile = id >> (ksb + 1), combo = id & ((2 << ksb) - 1);
  const int ks = combo >> 1, b = combo & 1;
  int r0, c0, gstride; size_t goff;
  tile_decode(tile, r0, c0, goff, gstride);
  const bool diag = (r0 == c0);
  const u16* Mb = Mbuf + (size_t)b * 1152 * HW;
  __shared__ u16 As[128 * 64];   // 16 KB
  __shared__ u16 Bs[128 * 64];   // 16 KB
  const int t = threadIdx.x;
  const int lane = t & 63, w = t >> 6;
  const int wr = w >> 1, wc = w & 1;
  const int m = lane & 15, quad = lane >> 4;
  const int lr = lane >> 3;
  const int lsl = ((lane & 7) ^ (lr & 7)) * 8;   // pre-swizzled global k-slot
  const int klen = 16384 >> ksb;
  const int kbase = ks * klen;
  f32x4 acc[4][4];
  #pragma unroll
  for (int i = 0; i < 4; i++)
    #pragma unroll
    for (int j = 0; j < 4; j++) acc[i][j] = (f32x4){0.f, 0.f, 0.f, 0.f};

  for (int s0 = kbase; s0 < kbase + klen; s0 += 64) {
    #pragma unroll
    for (int q = 0; q < 4; q++) {
      const int R0 = w * 32 + q * 8;
      gload16(Mb + (size_t)(r0 + R0 + lr) * HW + s0 + lsl, &As[R0 * 64]);
    }
    if (!diag) {
      #pragma unroll
      for (int q = 0; q < 4; q++) {
        const int R0 = w * 32 + q * 8;
        gload16(Mb + (size_t)(c0 + R0 + lr) * HW + s0 + lsl, &Bs[R0 * 64]);
      }
    }
    __syncthreads();
    const u16* Bb = diag ? As : Bs;
    #pragma unroll
    for (int kh = 0; kh < 2; kh++) {
      short8 af[4], bf[4];
      const int slot = ((quad + 4 * kh) ^ (m & 7)) * 8;
      #pragma unroll
      for (int i = 0; i < 4; i++)
        af[i] = *(const short8*)&As[(wr * 64 + i * 16 + m) * 64 + slot];
      #pragma unroll
      for (int j = 0; j < 4; j++)
        bf[j] = *(const short8*)&Bb[(wc * 64 + j * 16 + m) * 64 + slot];
      #pragma unroll
      for (int i = 0; i < 4; i++)
        #pragma unroll
        for (int j = 0; j < 4; j++)
          acc[i][j] = __builtin_amdgcn_mfma_f32_16x16x32_bf16(af[i], bf[j], acc[i][j], 0, 0, 0);
    }
    __syncthreads();
  }
  float* Gb = Gpart + (size_t)(b * nks + ks) * GP_SLOT + (size_t)tile * 16384;
  #pragma unroll
  for (int i = 0; i < 4; i++)
    #pragma unroll
    for (int j = 0; j < 4; j++) {
      int col = wc * 64 + j * 16 + m;
      #pragma unroll
      for (int r = 0; r < 4; r++) {
        int row = wr * 64 + i * 16 + quad * 4 + r;
        Gb[row * 128 + col] = acc[i][j][r];
      }
    }
}

// ---- greduce: sum nks K-slices per tile (L3-resident) -> compact G.
__global__ __launch_bounds__(256) void greduce(
    const float* __restrict__ Gpart, float* __restrict__ G, int nks) {
  const int chunk = blockIdx.x, tile = blockIdx.y, b = blockIdx.z;
  int r0, c0, gstride; size_t goff;
  tile_decode(tile, r0, c0, goff, gstride);
  const int t = threadIdx.x;
  const int e = chunk * 1024 + t * 4;
  const float* base = Gpart + (size_t)b * nks * GP_SLOT + (size_t)tile * 16384 + e;
  f32x4 acc = *(const f32x4*)base;
  for (int s = 1; s < nks; s++) acc += *(const f32x4*)(base + (size_t)s * GP_SLOT);
  const int row = e >> 7, col = e & 127;
  *(f32x4*)&G[(size_t)b * G_SZ + goff + (size_t)row * gstride + col] = acc;
}

// ------------------------------------- mirror S_j lower-left = upper-right^T
__global__ __launch_bounds__(256) void mirror_S(float* __restrict__ G) {
  const int j = blockIdx.x & 3, b = blockIdx.x >> 2;
  float* base = G + (size_t)b * G_SZ + G_S + (size_t)j * 65536;
  const int t = threadIdx.x;
  for (int e = t; e < 16384; e += 256) {
    int rr = e >> 7, cc = e & 127;
    base[(size_t)(128 + rr) * 256 + cc] = base[(size_t)cc * 256 + 128 + rr];
  }
}

// ------------------------------------------------------------------ Q row inv-norms
__global__ __launch_bounds__(64) void qnorm(
    const u16* __restrict__ qw, const float* __restrict__ G,
    float* __restrict__ invQ) {
  const int bn = blockIdx.x, b = bn >> 2, n = bn & 3;
  const int rq = threadIdx.x;
  const int i = rq & 3, q1r = rq >> 2;
  const u16* qr = qw + ((size_t)(i * 64) + 16 * n + q1r) * 32;
  float v[32];
  #pragma unroll
  for (int c = 0; c < 32; c++) v[c] = b2f(qr[c]);
  const float* D1 = G + (size_t)b * G_SZ;
  float ss = 0.f;
  for (int c = 0; c < 32; c++) {
    float tmp = 0.f;
    #pragma unroll
    for (int c2 = 0; c2 < 32; c2++) tmp = fmaf(v[c2], D1[(size_t)(32 * i + c2) * 128 + 32 * i + c], tmp);
    ss = fmaf(tmp, v[c], ss);
  }
  invQ[bn * 64 + rq] = 1.f / fmaxf(sqrtf(fmaxf(ss, 0.f)), 1e-12f);
}

// ---- knorm v2: 8 K-rows (same j) per block; S_j read ONCE per block.
__global__ __launch_bounds__(256) void knorm(
    const u16* __restrict__ kw, const float* __restrict__ G,
    float* __restrict__ invK) {
  const int jj = blockIdx.x;          // 0..63
  const int j = jj & 3, kkg = jj >> 2;
  const int n = blockIdx.y, b = blockIdx.z;
  const int t = threadIdx.x;
  __shared__ float vs[8][256];        // 8 K-rows
  for (int e = t; e < 2048; e += 256) {
    int r = e >> 8, c = e & 255;
    vs[r][c] = b2f(kw[((size_t)(j * 512) + 128 * n + kkg * 8 + r) * 256 + c]);
  }
  __syncthreads();
  const float* S = G + (size_t)b * G_SZ + G_S + (size_t)j * 65536;
  float acc[8];
  #pragma unroll
  for (int r = 0; r < 8; r++) acc[r] = 0.f;
  for (int c2 = 0; c2 < 256; c2++) {
    float sv = S[(size_t)c2 * 256 + t];
    #pragma unroll
    for (int r = 0; r < 8; r++) acc[r] = fmaf(vs[r][c2], sv, acc[r]);
  }
  #pragma unroll
  for (int r = 0; r < 8; r++) acc[r] *= vs[r][t];
  __shared__ float red[8][4];
  const int wv = t >> 6, lane = t & 63;
  #pragma unroll
  for (int r = 0; r < 8; r++) {
    float v = wave_sum(acc[r]);
    if (lane == 0) red[r][wv] = v;
  }
  __syncthreads();
  if (t < 8) {
    float tot = fmaxf(red[t][0] + red[t][1] + red[t][2] + red[t][3], 0.f);
    invK[(size_t)(b * 4 + n) * 512 + 4 * (kkg * 8 + t) + j] =
        1.f / fmaxf(sqrtf(tot), 1e-12f);
  }
}

// ---------- score2 v3: KD = D2_j . kw_half^T, then q_w.KD; epilogue fuses
// iQ/iK/isc scaling + InstanceNorm partial stats (atomics into sstat).
__global__ __launch_bounds__(256) void score2(
    const u16* __restrict__ qw, const u16* __restrict__ kw,
    const float* __restrict__ G, const float* __restrict__ invQ,
    const float* __restrict__ invK, float* __restrict__ score,
    float* __restrict__ sstat) {
  const int jj = blockIdx.x;        // 0..7
  const int j = jj >> 1, half = jj & 1;
  const int n = blockIdx.y, b = blockIdx.z;
  const float* D2 = G + (size_t)b * G_SZ + G_D2;
  const u16* kwb = kw + ((size_t)(j * 512) + 128 * n + half * 64) * 256;  // 64 rows
  __shared__ float As[64][132];
  __shared__ u16 Bs[64][68];
  __shared__ float KD[128][68];
  __shared__ float qws[64][32];
  const int t = threadIdx.x;
  const int tx = t & 7, ty = t >> 3;
  float acc[4][8];
  #pragma unroll
  for (int i = 0; i < 4; i++)
    #pragma unroll
    for (int u = 0; u < 8; u++) acc[i][u] = 0.f;
  for (int ch0 = 0; ch0 < 256; ch0 += 64) {
    for (int e = t; e < 8192; e += 256) {
      int r = e >> 6, kc = e & 63;
      As[kc][r] = D2[(size_t)r * 1024 + j * 256 + ch0 + kc];
    }
    for (int e = t; e < 4096; e += 256) {
      int r = e >> 6, kc = e & 63;
      Bs[kc][r] = kwb[(size_t)r * 256 + ch0 + kc];
    }
    __syncthreads();
    #pragma unroll 4
    for (int kc = 0; kc < 64; kc++) {
      float a[4];
      #pragma unroll
      for (int i = 0; i < 4; i++) a[i] = As[kc][ty * 4 + i];
      float bb[8];
      #pragma unroll
      for (int u = 0; u < 8; u++) bb[u] = b2f(Bs[kc][tx * 8 + u]);
      #pragma unroll
      for (int i = 0; i < 4; i++)
        #pragma unroll
        for (int u = 0; u < 8; u++) acc[i][u] = fmaf(a[i], bb[u], acc[i][u]);
    }
    __syncthreads();
  }
  #pragma unroll
  for (int i = 0; i < 4; i++)
    #pragma unroll
    for (int u = 0; u < 8; u++) KD[ty * 4 + i][tx * 8 + u] = acc[i][u];
  for (int e = t; e < 2048; e += 256) {
    int q = e >> 5, c = e & 31;
    int i = q & 3, q1r = q >> 2;
    qws[q][c] = b2f(qw[((size_t)(i * 64) + 16 * n + q1r) * 32 + c]);
  }
  __syncthreads();
  const int bn = b * 4 + n;
  float* sb = score + (size_t)bn * 64 * 512;
  const float* iQ = invQ + bn * 64;
  const float* iK = invK + (size_t)bn * 512;
  const float isc = 1.f / 128.f;
  float lsum = 0.f, lss = 0.f;
  for (int e = t; e < 4096; e += 256) {
    int q = e >> 6, kkl = e & 63;
    int i = q & 3;
    float s = 0.f;
    #pragma unroll
    for (int c = 0; c < 32; c++) s = fmaf(qws[q][c], KD[i * 32 + c][kkl], s);
    int col = 4 * (half * 64 + kkl) + j;
    float v = s * iQ[q] * iK[col] * isc;
    sb[(size_t)q * 512 + col] = v;
    lsum += v; lss += v * v;
  }
  lsum = wave_sum(lsum); lss = wave_sum(lss);
  __shared__ float redp[8];
  if ((t & 63) == 0) { redp[t >> 6] = lsum; redp[4 + (t >> 6)] = lss; }
  __syncthreads();
  if (t == 0) {
    atomicAdd(&sstat[bn * 2],     redp[0] + redp[1] + redp[2] + redp[3]);
    atomicAdd(&sstat[bn * 2 + 1], redp[4] + redp[5] + redp[6] + redp[7]);
  }
}

// ------- in_softmax v2: normalize + row softmax only (stats precomputed);
__global__ __launch_bounds__(256) void in_softmax(
    float* __restrict__ score, const float* __restrict__ sstat) {
  const int bn = blockIdx.y, rg = blockIdx.x;
  float* sb = score + (size_t)bn * 64 * 512;
  const int t = threadIdx.x;
  float mean = sstat[bn * 2] * (1.f / 32768.f);
  float var = sstat[bn * 2 + 1] * (1.f / 32768.f) - mean * mean;
  float istd = rsqrtf(var + 1e-5f);
  const int wv = t >> 6, lane = t & 63;
  for (int rr = wv; rr < 8; rr += 4) {
    int r = rg * 8 + rr;
    float z[8];
    float m = -1e30f;
    #pragma unroll
    for (int jx = 0; jx < 8; jx++) {
      z[jx] = (sb[(size_t)r * 512 + lane + 64 * jx] - mean) * istd;
      m = fmaxf(m, z[jx]);
    }
    m = wave_max(m);
    float sloc = 0.f;
    #pragma unroll
    for (int jx = 0; jx < 8; jx++) { z[jx] = expf(z[jx] - m); sloc += z[jx]; }
    sloc = wave_sum(sloc);
    float rinv = 1.f / sloc;
    #pragma unroll
    for (int jx = 0; jx < 8; jx++) sb[(size_t)r * 512 + lane + 64 * jx] = z[jx] * rinv;
  }
}

// --------- attnW2 v2: grid (j*4+n, q0, b); thread = out channel; coalesced vw reads
__global__ __launch_bounds__(256) void attnW2(
    const float* __restrict__ attn, const u16* __restrict__ vw,
    float* __restrict__ W2) {
  const int j = blockIdx.x >> 2, n = blockIdx.x & 3;
  const int q0 = blockIdx.y * 8, b = blockIdx.z, bn = b * 4 + n;
  const float* ab = attn + (size_t)bn * 64 * 512;
  const int t = threadIdx.x;  // = ch 0..255
  __shared__ float at_s[8][128];
  for (int e = t; e < 1024; e += 256) {
    int qg = e >> 7, kk = e & 127;
    at_s[qg][kk] = ab[(size_t)(q0 + qg) * 512 + 4 * kk + j];
  }
  __syncthreads();
  float acc[8];
  #pragma unroll
  for (int qg = 0; qg < 8; qg++) acc[qg] = 0.f;
  const u16* vcol = vw + ((size_t)(j * 512) + 128 * n) * 256 + t;
  for (int kk = 0; kk < 128; kk++) {
    float v = b2f(vcol[(size_t)kk * 256]);
    #pragma unroll
    for (int qg = 0; qg < 8; qg++) acc[qg] = fmaf(at_s[qg][kk], v, acc[qg]);
  }
  #pragma unroll
  for (int qg = 0; qg < 8; qg++)
    W2[((size_t)bn * 64 + q0 + qg) * 1024 + j * 256 + t] = acc[qg];
}

// ---- wfin v2: Wfin16[b][o][jc] = bf16(out_w . W2). Block = (jc-tile 256,
// o-tile 16, b). Coalesced W2 column reads (lane = jc), ow rows LDS-broadcast.
__global__ __launch_bounds__(256) void wfin_k(
    const u16* __restrict__ ow, const float* __restrict__ W2,
    u16* __restrict__ Wfin16) {
  const int jc0 = blockIdx.x * 256;
  const int o0 = blockIdx.y * 16;
  const int b = blockIdx.z;
  __shared__ float ows[16][257];
  const int t = threadIdx.x;
  for (int e = t; e < 4096; e += 256) {
    int o = e >> 8, c = e & 255;
    ows[o][c] = b2f(ow[(size_t)(o0 + o) * 256 + c]);
  }
  __syncthreads();
  const float* W2b = W2 + (size_t)b * 256 * 1024 + jc0 + t;
  float acc[16];
  #pragma unroll
  for (int o = 0; o < 16; o++) acc[o] = 0.f;
  for (int c = 0; c < 256; c++) {
    float w2v = W2b[(size_t)c * 1024];
    #pragma unroll
    for (int o = 0; o < 16; o++) acc[o] = fmaf(ows[o][c], w2v, acc[o]);
  }
  u16* dst = Wfin16 + (size_t)b * 256 * 1024 + jc0 + t;
  #pragma unroll
  for (int o = 0; o < 16; o++)
    dst[(size_t)(o0 + o) * 1024] = f2b(acc[o]);
}

// ----- y_gemm v6: dbuf single-barrier pipeline; A via global_load_lds(16B)
// +XOR swizzle; B reg-transpose with STATIC indices into 3-term-XOR LDS
// layout: slot(chunk,row) = chunk ^ (row&7) ^ ((row>>3)&7).
__global__ __launch_bounds__(256) void y_gemm_mfma(
    const u16* __restrict__ Wfin16, const u16* __restrict__ Mbuf,
    u16* __restrict__ ybuf) {
  const int b = blockIdx.y, col0 = blockIdx.x * 64;
  __shared__ u16 As[2][256 * 64];  // 64 KB  [o-row][k-slot swizzled: c^(r&7)]
  __shared__ u16 Bs[2][64 * 64];   // 16 KB  [s-col][k-slot swizzled: c^(r&7)^(r>>3)]
  const u16* Ab = Wfin16 + (size_t)b * 256 * 1024;
  const u16* Mb = Mbuf + (size_t)b * 1152 * HW + (size_t)128 * HW;
  const int t = threadIdx.x;
  const int lane = t & 63, w = t >> 6;
  const int m = lane & 15, quad = lane >> 4;
  const int kp = t >> 3, cs = t & 7;           // B: k-pair 0..31, s-chunk 0..7
  const int lr = lane >> 3;                    // A staging: row within 8-group
  const int lsl = ((lane & 7) ^ (lr & 7)) * 8; // pre-swizzled global k-slot
  f32x4 acc[4][4];
  #pragma unroll
  for (int i = 0; i < 4; i++)
    #pragma unroll
    for (int j = 0; j < 4; j++) acc[i][j] = (f32x4){0.f, 0.f, 0.f, 0.f};

  uint4 v0, v1;
  auto stageA = [&](int buf, int k0c) {
    #pragma unroll
    for (int q = 0; q < 8; q++)
      gload16(&Ab[(size_t)(w * 64 + q * 8 + lr) * 1024 + k0c + lsl],
              &As[buf][(w * 64 + q * 8) * 64]);
  };
  auto loadB = [&](int k0c) {
    v0 = *(const uint4*)&Mb[(size_t)(k0c + 2 * kp) * HW + col0 + cs * 8];
    v1 = *(const uint4*)&Mb[(size_t)(k0c + 2 * kp + 1) * HW + col0 + cs * 8];
  };
  auto writeB = [&](int buf) {
    u16 t0[8], t1[8];
    *(uint4*)t0 = v0; *(uint4*)t1 = v1;
    const int ksl = kp >> 2, kin = (2 * kp) & 7;
    #pragma unroll
    for (int uu = 0; uu < 8; uu++) {        // STATIC index — registers
      int r = cs * 8 + uu;                  // r&7 = uu, r>>3 = cs
      u32 pair = (u32)t0[uu] | ((u32)t1[uu] << 16);
      *(u32*)&Bs[buf][r * 64 + (((ksl ^ uu ^ cs) & 7) << 3) + kin] = pair;
    }
  };

  stageA(0, 0);
  loadB(0);
  writeB(0);
  __syncthreads();

  int cur = 0;
  for (int step = 0; step < 16; step++) {
    const int nxt = cur ^ 1;
    if (step < 15) {
      stageA(nxt, (step + 1) * 64);
      loadB((step + 1) * 64);
    }
    #pragma unroll
    for (int kh = 0; kh < 2; kh++) {
      short8 af[4], bf[4];
      const int slotA = ((4 * kh + quad) ^ (m & 7)) * 8;
      #pragma unroll
      for (int i = 0; i < 4; i++)
        af[i] = *(const short8*)&As[cur][(w * 64 + i * 16 + m) * 64 + slotA];
      #pragma unroll
      for (int j = 0; j < 4; j++) {
        const int row = j * 16 + m;
        const int slotB = (((4 * kh + quad) ^ (row & 7) ^ ((row >> 3) & 7)) & 7) * 8;
        bf[j] = *(const short8*)&Bs[cur][row * 64 + slotB];
      }
      #pragma unroll
      for (int i = 0; i < 4; i++)
        #pragma unroll
        for (int j = 0; j < 4; j++)
          acc[i][j] = __builtin_amdgcn_mfma_f32_16x16x32_bf16(af[i], bf[j], acc[i][j], 0, 0, 0);
    }
    if (step < 15) {
      writeB(nxt);
      __syncthreads();
      cur = nxt;
    }
  }
  #pragma unroll
  for (int i = 0; i < 4; i++)
    #pragma unroll
    for (int j = 0; j < 4; j++) {
      int col = col0 + j * 16 + m;
      #pragma unroll
      for (int r = 0; r < 4; r++) {
        int row = w * 64 + i * 16 + quad * 4 + r;
        ybuf[((size_t)b * 256 + row) * HW + col] = f2b(acc[i][j][r]);
      }
    }
}

// ---------------------------------------------------------------- BatchNorm
__global__ __launch_bounds__(256) void bn_stats(
    const u16* __restrict__ y, float* __restrict__ st) {
  const int o = blockIdx.x;
  const int t = threadIdx.x;
  float sum = 0.f, ss = 0.f;
  for (int bb = 0; bb < 2; bb++) {
    const u16* p = y + ((size_t)bb * 256 + o) * HW;
    for (int e = t; e < HW / 8; e += 256) {
      uint4 v = ((const uint4*)p)[e];
      float f[8];
      unpack8(v, f);
      #pragma unroll
      for (int k = 0; k < 8; k++) { sum += f[k]; ss += f[k] * f[k]; }
    }
  }
  __shared__ float red[8];
  sum = wave_sum(sum); ss = wave_sum(ss);
  if ((t & 63) == 0) { red[t >> 6] = sum; red[4 + (t >> 6)] = ss; }
  __syncthreads();
  if (t == 0) {
    float mean = (red[0] + red[1] + red[2] + red[3]) / 32768.f;
    float var = (red[4] + red[5] + red[6] + red[7]) / 32768.f - mean * mean;
    st[o * 2] = mean;
    st[o * 2 + 1] = rsqrtf(var + 1e-5f);
  }
}

__global__ __launch_bounds__(256) void bn_apply(
    const u16* __restrict__ y, const float* __restrict__ st,
    const u16* __restrict__ gamma, const u16* __restrict__ beta,
    const int* __restrict__ flag, void* __restrict__ out) {
  const int idx8 = blockIdx.x * 256 + threadIdx.x;
  const int r = idx8 >> 11;
  const int o = r & 255;
  float mean = st[o * 2], istd = st[o * 2 + 1];
  float g = b2f(gamma[o]), be = b2f(beta[o]);
  uint4 v = ((const uint4*)y)[idx8];
  float f[8];
  unpack8(v, f);
  float rr[8];
  #pragma unroll
  for (int k = 0; k < 8; k++) rr[k] = fmaxf((f[k] - mean) * istd * g + be, 0.f);
  if (*flag) {
    float* of = (float*)out + (size_t)idx8 * 8;
    *(float4*)of = make_float4(rr[0], rr[1], rr[2], rr[3]);
    *(float4*)(of + 4) = make_float4(rr[4], rr[5], rr[6], rr[7]);
  } else {
    u32 p0 = (u32)f2b(rr[0]) | ((u32)f2b(rr[1]) << 16);
    u32 p1 = (u32)f2b(rr[2]) | ((u32)f2b(rr[3]) << 16);
    u32 p2 = (u32)f2b(rr[4]) | ((u32)f2b(rr[5]) << 16);
    u32 p3 = (u32)f2b(rr[6]) | ((u32)f2b(rr[7]) << 16);
    ((uint4*)out)[idx8] = make_uint4(p0, p1, p2, p3);
  }
}

// ----------------------------------------------------------------------------
extern "C" void kernel_launch(void* const* d_in, const int* in_sizes, int n_in,
                              void* d_out, int out_size, void* d_ws, size_t ws_size,
                              hipStream_t stream) {
  float* G     = (float*)d_ws;           // 819,200 f32 (2 x G_SZ)
  float* score = G + 819200;             // 262,144
  float* invQ  = score + 262144;         // 512
  float* invK  = invQ + 512;             // 4,096
  float* W2    = invK + 4096;            // 524,288
  float* Wfin  = W2 + 524288;            // slot reused: u16 Wfin16
  float* bnst  = Wfin + 524288;          // 512
  float* sstat = bnst + 512;             // 16 (IN stats) + 16 zero-page
  float* zbuf  = sstat + 16;             // 64 B zeros (edge-px gload source)
  int* flag    = (int*)(zbuf + 16);      // 16
  u16* Sbuf    = (u16*)(flag + 16);      // S_TOTAL u16
  u16* Mbuf    = Sbuf + S_TOTAL;         // 37,748,736 u16
  u16* ybuf    = Mbuf + 37748736;        // 8,388,608 u16 (16 MB)
  u16* Wfin16  = (u16*)Wfin;
  float* lgbuf = (float*)ybuf;           // alias: 4 MB [z][s][8], dead before gram
  u16* cenT    = (u16*)(lgbuf + 1048576);// alias: 2 MB [b][s][ci], dead before gram
  float* Gpart = (float*)ybuf;           // alias: partial-G; dead after greduce

  const int ksb = 4;  // ks=16: R23 measured ks=32 HBM-bound (L3 eviction)

  probe<<<1, 64, 0, stream>>>((const u32*)d_in[10], flag);
  convert_all<<<dim3(1024, 1, 12), 256, 0, stream>>>(
      d_in[0], d_in[1], d_in[2], d_in[3], d_in[4], d_in[5], d_in[6], d_in[7],
      d_in[8], d_in[9], d_in[10], d_in[11], Sbuf, flag);
  hipMemsetAsync(sstat, 0, 32 * sizeof(float), stream);  // sstat + zbuf

  transp<<<dim3(64, 2), 256, 0, stream>>>(Sbuf + S_CEN, cenT);
  sur_w<<<dim3(128, 8), 256, 0, stream>>>(
      cenT, Sbuf + S_W1, Sbuf + S_B1, Sbuf + S_W2, (const u16*)zbuf, lgbuf);
  sur_scatter<<<dim3(32, 4, 8), 256, 0, stream>>>(
      Sbuf + S_CEN, lgbuf, Sbuf + S_B2, Sbuf + S_SW, Mbuf);
  gram_mfma<<<21 << (ksb + 1), 256, 0, stream>>>(Mbuf, Gpart, ksb);
  greduce<<<dim3(16, 21, 2), 256, 0, stream>>>(Gpart, G, 1 << ksb);
  mirror_S<<<8, 256, 0, stream>>>(G);
  qnorm<<<8, 64, 0, stream>>>(Sbuf + S_QW, G, invQ);
  knorm<<<dim3(64, 4, 2), 256, 0, stream>>>(Sbuf + S_KW, G, invK);
  score2<<<dim3(8, 4, 2), 256, 0, stream>>>(
      Sbuf + S_QW, Sbuf + S_KW, G, invQ, invK, score, sstat);
  in_softmax<<<dim3(8, 8), 256, 0, stream>>>(score, sstat);
  attnW2<<<dim3(16, 8, 2), 256, 0, stream>>>(score, Sbuf + S_VW, W2);
  wfin_k<<<dim3(4, 16, 2), 256, 0, stream>>>(Sbuf + S_OW, W2, Wfin16);
  y_gemm_mfma<<<dim3(256, 2), 256, 0, stream>>>(Wfin16, Mbuf, ybuf);
  bn_stats<<<256, 256, 0, stream>>>(ybuf, bnst);
  bn_apply<<<4096, 256, 0, stream>>>(ybuf, bnst, Sbuf + S_GAMMA, Sbuf + S_BETA,
                                     flag, d_out);
}